// Round 4
// baseline (453.999 us; speedup 1.0000x reference)
//
#include <hip/hip_runtime.h>
#include <stdint.h>

typedef unsigned short ushort_t;
typedef unsigned int uint_t;

#define B_SZ 16
#define CIN 64
#define COUT 64
#define N_SZ 1024
#define L_SZ 12
#define CL 768            // COUT * L_SZ
#define NL 12288          // N_SZ * L_SZ
#define ALPHA 0.2f

typedef __bf16 bf16x8 __attribute__((ext_vector_type(8)));
typedef float floatx4 __attribute__((ext_vector_type(4)));
typedef _Float16 half8 __attribute__((ext_vector_type(8)));
typedef _Float16 half4 __attribute__((ext_vector_type(4)));

__device__ __forceinline__ ushort_t f2bf(float x) {
    uint_t u = __float_as_uint(x);
    u += 0x7fffu + ((u >> 16) & 1u);
    return (ushort_t)(u >> 16);
}
__device__ __forceinline__ float bf2f(ushort_t h) {
    return __uint_as_float(((uint_t)h) << 16);
}

// async global->LDS, 16B per lane; LDS dest must be wave-uniform base + lane*16
#define ASYNC16(ldsp, gp)                                                \
    __builtin_amdgcn_global_load_lds(                                    \
        (const __attribute__((address_space(1))) void*)(gp),             \
        (__attribute__((address_space(3))) void*)(ldsp), 16, 0, 0)

// ---------------------------------------------------------------------------
// K1: conv0 (1x3, pad 1) + bias + fused f, f16 MFMA im2col GEMM.
// This is the harness-verified round-1 kernel (256 thr, 4 waves = 4 co-tiles,
// one 96-position im2col sub-tile in LDS, 38.4 KB) with ONE structural
// change: instead of 128 blocks/batch each doing one 96-p tile, 16
// blocks/batch each iterate over 8 CONSECUTIVE sub-tiles (for g < 8), so a
// block owns 768 positions = 64 consecutive n. Fix target: round-1 measured
// WRITE_SIZE 225 MB (9x ideal) because each (co,l) Xt row got only 16 B per
// 128 B line per block, and the 8 line-sharing blocks sat on different XCDs
// (XCD = wgid % 8) -> partial-line HBM RMW. Now one block fills the full
// 128 B line of every (co,l) row within a few µs on one XCD's L2.
// Weights/bias hoisted out of the g-loop. Grid (16, B) = 256 blocks.
// Sub-tile edges: 96 % 12 == 0, so sub-tile edge columns are exactly conv
// L-padding; zeroed once before the loop, never overwritten.
// ---------------------------------------------------------------------------
__global__ __launch_bounds__(256, 4) void conv_mfma_kernel(
    const float* __restrict__ inp, const float* __restrict__ w0,
    const float* __restrict__ b0, const float* __restrict__ w1,
    ushort_t* __restrict__ Xt, float* __restrict__ fout)
{
    __shared__ _Float16 Bs[96 * 200];   // [p][k 0..191, pad to 200] 38400 B
    __shared__ float fredcol[96];

    const int bx = blockIdx.x;          // 64-n tile (0..15)
    const int b  = blockIdx.y;
    const int t  = threadIdx.x;
    const int lane = t & 63, w = t >> 6;     // w = co-tile of this wave
    const int rr = lane & 15, kc = lane >> 4;
    const half4 hz = (half4)(_Float16)0.f;

    if (t < 96) fredcol[t] = 0.f;
    // tile-edge zero columns: written once, never overwritten by staging
    if (t < 16) *(half4*)&Bs[0 * 200 + t * 4] = hz;                    // kt=0, p=0
    else if (t < 32) *(half4*)&Bs[95 * 200 + 128 + (t - 16) * 4] = hz; // kt=2, p=95

    // ---- A fragments (weights) once per block; w0 layout [co][ci][kt] ----
    const int co_r = w * 16 + rr;
    half8 af[6];
#pragma unroll
    for (int ch = 0; ch < 6; ch++) {
        const int kt = ch >> 1;
        const int ci0 = (ch & 1) * 32 + kc * 8;
        const float* wp = w0 + co_r * 192 + ci0 * 3 + kt;
#pragma unroll
        for (int e = 0; e < 8; e++) af[ch][e] = (_Float16)wp[e * 3];
    }

    float b0v[4], w1v[4][12];
#pragma unroll
    for (int r = 0; r < 4; r++) {
        b0v[r] = b0[w * 16 + kc * 4 + r];
#pragma unroll
        for (int l = 0; l < 12; l++) w1v[r][l] = w1[(w * 16 + kc * 4 + r) * 12 + l];
    }

    const float* ibase = inp + (size_t)b * CIN * NL;
    ushort_t* XtB = Xt + (size_t)b * CL * N_SZ;

#pragma unroll 1
    for (int g = 0; g < 8; g++) {
        const int p0 = bx * 768 + g * 96;

        // ---- stage im2col sub-tile: 1536 tasks = 96 p x 16 ci-groups ----
#pragma unroll
        for (int i = 0; i < 6; i++) {
            const int idx = i * 256 + t;
            const int p = idx % 96;
            const int cig = idx / 96;
            const int l = p % 12;
            const float* src = ibase + (size_t)(cig * 4) * NL + p0 + p;
            half4 hv;
            hv[0] = (_Float16)src[0];
            hv[1] = (_Float16)src[NL];
            hv[2] = (_Float16)src[2 * NL];
            hv[3] = (_Float16)src[3 * NL];
            // kt=1: B[64+ci][p]
            *(half4*)&Bs[p * 200 + 64 + cig * 4] = hv;
            // kt=0: B[ci][p+1], zero across n-row boundary
            if (p + 1 < 96) {
                half4 v0 = hv; if (l == 11) v0 = hz;
                *(half4*)&Bs[(p + 1) * 200 + cig * 4] = v0;
            }
            // kt=2: B[128+ci][p-1], zero across n-row boundary
            if (p >= 1) {
                half4 v2 = hv; if (l == 0) v2 = hz;
                *(half4*)&Bs[(p - 1) * 200 + 128 + cig * 4] = v2;
            }
        }
        __syncthreads();

        // ---- MFMA: 6 p-frags x 6 k-chunks per wave ----
        floatx4 acc[6];
#pragma unroll
        for (int fp = 0; fp < 6; fp++) acc[fp] = (floatx4)0.f;
#pragma unroll
        for (int fp = 0; fp < 6; fp++) {
            const _Float16* brow = &Bs[(fp * 16 + rr) * 200 + kc * 8];
#pragma unroll
            for (int ch = 0; ch < 6; ch++) {
                const half8 bf = *(const half8*)(brow + ch * 32);
                acc[fp] = __builtin_amdgcn_mfma_f32_16x16x32_f16(af[ch], bf, acc[fp], 0, 0, 0);
            }
        }

        // ---- epilogue: bias, Xt bf16 store, partial f ----
#pragma unroll
        for (int fp = 0; fp < 6; fp++) {
            const int pcol = fp * 16 + rr;
            const int pg = p0 + pcol;
            const int n = pg / 12;
            const int l = pcol % 12;          // p0 is a multiple of 12
            float fc = 0.f;
#pragma unroll
            for (int r = 0; r < 4; r++) {
                const int co = w * 16 + kc * 4 + r;
                const float x = acc[fp][r] + b0v[r];
                fc += x * w1v[r][l];
                XtB[(size_t)(co * 12 + l) * N_SZ + n] = f2bf(x);
            }
            atomicAdd(&fredcol[pcol], fc);
        }
        __syncthreads();

        // ---- f for the 8 n of this sub-tile; same threads re-zero ----
        if (t < 8) {
            float s = 0.f;
#pragma unroll
            for (int j = 0; j < 12; j++) s += fredcol[t * 12 + j];
            fout[b * N_SZ + bx * 64 + g * 8 + t] = s;
#pragma unroll
            for (int j = 0; j < 12; j++) fredcol[t * 12 + j] = 0.f;
        }
        // next staging writes to Bs are safe: all MFMA reads of this g
        // completed before the barrier above; fredcol re-zero is ordered
        // against next g's atomicAdds by next g's stage barrier.
    }
}

// ---------------------------------------------------------------------------
// K2: z = leaky(f_i + f_j) + adj; row softmax; store S bf16 (row-major).
// Block: 256 thr per row; grid (N, B).
// ---------------------------------------------------------------------------
__global__ __launch_bounds__(256) void softmax_kernel(
    const float* __restrict__ adj, const float* __restrict__ f,
    ushort_t* __restrict__ Sb)
{
    __shared__ float smx[4], sms[4];
    const int i = blockIdx.x, b = blockIdx.y, t = threadIdx.x;
    const int lane = t & 63, wv = t >> 6;

    const float* frow = f + b * N_SZ;
    const float fi = frow[i];
    const float4 fj = *(const float4*)(frow + 4 * t);
    const float4 av = *(const float4*)(adj + ((size_t)b * N_SZ + i) * N_SZ + 4 * t);

    float z[4];
    z[0] = fi + fj.x; z[1] = fi + fj.y; z[2] = fi + fj.z; z[3] = fi + fj.w;
#pragma unroll
    for (int k = 0; k < 4; k++) z[k] = (z[k] >= 0.f) ? z[k] : ALPHA * z[k];
    z[0] += av.x; z[1] += av.y; z[2] += av.z; z[3] += av.w;

    float mx = fmaxf(fmaxf(z[0], z[1]), fmaxf(z[2], z[3]));
#pragma unroll
    for (int o = 32; o; o >>= 1) mx = fmaxf(mx, __shfl_xor(mx, o, 64));
    if (lane == 0) smx[wv] = mx;
    __syncthreads();
    mx = fmaxf(fmaxf(smx[0], smx[1]), fmaxf(smx[2], smx[3]));

    float e[4], s = 0.f;
#pragma unroll
    for (int k = 0; k < 4; k++) { e[k] = __expf(z[k] - mx); s += e[k]; }
#pragma unroll
    for (int o = 32; o; o >>= 1) s += __shfl_xor(s, o, 64);
    if (lane == 0) sms[wv] = s;
    __syncthreads();
    s = sms[0] + sms[1] + sms[2] + sms[3];
    const float inv = 1.0f / s;

    const uint_t p0 = (uint_t)f2bf(e[0] * inv) | ((uint_t)f2bf(e[1] * inv) << 16);
    const uint_t p1 = (uint_t)f2bf(e[2] * inv) | ((uint_t)f2bf(e[3] * inv) << 16);
    uint2 pk; pk.x = p0; pk.y = p1;
    *(uint2*)&Sb[((size_t)b * N_SZ + i) * N_SZ + 4 * t] = pk;
}

// ---------------------------------------------------------------------------
// K3: attention output = S^T, bf16 -> fp32, LDS 64x64 tile transpose.
// grid (N/64, N/64, B): x = i-tile, y = j-tile.
// ---------------------------------------------------------------------------
__global__ __launch_bounds__(256) void att_transpose_kernel(
    const ushort_t* __restrict__ Sb, float* __restrict__ att)
{
    __shared__ float T[64][65];
    const int b = blockIdx.z;
    const int i0 = blockIdx.x * 64, j0 = blockIdx.y * 64;
    const int t = threadIdx.x;

#pragma unroll
    for (int ph = 0; ph < 2; ph++) {
        const int idx = ph * 256 + t;
        const int r = idx >> 3, c8 = (idx & 7) * 8;
        const uint4 v = *(const uint4*)(Sb + ((size_t)b * N_SZ + i0 + r) * N_SZ + j0 + c8);
        T[r][c8 + 0] = bf2f((ushort_t)(v.x & 0xffff));
        T[r][c8 + 1] = bf2f((ushort_t)(v.x >> 16));
        T[r][c8 + 2] = bf2f((ushort_t)(v.y & 0xffff));
        T[r][c8 + 3] = bf2f((ushort_t)(v.y >> 16));
        T[r][c8 + 4] = bf2f((ushort_t)(v.z & 0xffff));
        T[r][c8 + 5] = bf2f((ushort_t)(v.z >> 16));
        T[r][c8 + 6] = bf2f((ushort_t)(v.w & 0xffff));
        T[r][c8 + 7] = bf2f((ushort_t)(v.w >> 16));
    }
    __syncthreads();
#pragma unroll
    for (int ph = 0; ph < 4; ph++) {
        const int idx = ph * 256 + t;
        const int jr = idx >> 4, i4 = (idx & 15) * 4;
        float4 o;
        o.x = T[i4 + 0][jr]; o.y = T[i4 + 1][jr];
        o.z = T[i4 + 2][jr]; o.w = T[i4 + 3][jr];
        *(float4*)(att + ((size_t)b * N_SZ + j0 + jr) * N_SZ + i0 + i4) = o;
    }
}

// ---------------------------------------------------------------------------
// K4: per-batch GEMM  C[q,m] = sum_n S[q,n] * Xt[m,n], m=(co*12+l).
// 128x128 block tile, BK=64, 4 waves in 2x2, each wave 64x64 via 4x4
// mfma_f32_16x16x32_bf16. Staging via global_load_lds width=16. LDS 32KB.
// Epilogue scatters into NCHW out. grid (CL/128=6, N/128=8, B).
// ---------------------------------------------------------------------------
__global__ __launch_bounds__(256) void gemm2_kernel(
    const ushort_t* __restrict__ Sb, const ushort_t* __restrict__ Xt,
    float* __restrict__ out)
{
    __shared__ ushort_t As[1024 * 8];
    __shared__ ushort_t Bs[1024 * 8];
    const int b = blockIdx.z;
    const int m0 = blockIdx.x * 128, q0 = blockIdx.y * 128;
    const int t = threadIdx.x;
    const int lane = t & 63, wv = t >> 6;
    const int wq = wv >> 1, wm = wv & 1;
    const int kc = lane >> 4, rr = lane & 15;

    const ushort_t* Sbase = Sb + (size_t)b * N_SZ * N_SZ;
    const ushort_t* Xbase = Xt + (size_t)b * CL * N_SZ;

    floatx4 acc[4][4];
#pragma unroll
    for (int i = 0; i < 4; i++)
#pragma unroll
        for (int j = 0; j < 4; j++) acc[i][j] = (floatx4)0.f;

    for (int k0 = 0; k0 < N_SZ; k0 += 64) {
        __syncthreads();
#pragma unroll
        for (int c = 0; c < 4; c++) {
            const int u = c * 256 + t;
            const int r = u & 127, kcs = u >> 7;
            ASYNC16(&As[u * 8], Sbase + (size_t)(q0 + r) * N_SZ + k0 + kcs * 8);
            ASYNC16(&Bs[u * 8], Xbase + (size_t)(m0 + r) * N_SZ + k0 + kcs * 8);
        }
        __syncthreads();

#pragma unroll
        for (int kk = 0; kk < 2; kk++) {
            bf16x8 af[4], bfr[4];
#pragma unroll
            for (int i = 0; i < 4; i++) {
                af[i]  = *(const bf16x8*)&As[((kk * 4 + kc) * 128 + wq * 64 + i * 16 + rr) * 8];
                bfr[i] = *(const bf16x8*)&Bs[((kk * 4 + kc) * 128 + wm * 64 + i * 16 + rr) * 8];
            }
#pragma unroll
            for (int i = 0; i < 4; i++)
#pragma unroll
                for (int j = 0; j < 4; j++)
                    acc[i][j] = __builtin_amdgcn_mfma_f32_16x16x32_bf16(
                        af[i], bfr[j], acc[i][j], 0, 0, 0);
        }
    }

    // epilogue: C row = q (= kc*4 + reg within frag), col = m (= rr within frag)
#pragma unroll
    for (int j = 0; j < 4; j++) {
        const int m = m0 + wm * 64 + j * 16 + rr;
        const int co = m / 12, l = m - co * 12;
        float* ob = out + (size_t)(b * COUT + co) * (N_SZ * L_SZ) + l;
#pragma unroll
        for (int i = 0; i < 4; i++) {
            const int q = q0 + wq * 64 + i * 16 + kc * 4;
#pragma unroll
            for (int r2 = 0; r2 < 4; r2++)
                ob[(size_t)(q + r2) * 12] = acc[i][j][r2];
        }
    }
}

// ---------------------------------------------------------------------------
extern "C" void kernel_launch(void* const* d_in, const int* in_sizes, int n_in,
                              void* d_out, int out_size, void* d_ws, size_t ws_size,
                              hipStream_t stream)
{
    const float* inp = (const float*)d_in[0];
    const float* adj = (const float*)d_in[1];
    const float* w0  = (const float*)d_in[2];
    const float* b0  = (const float*)d_in[3];
    const float* w1  = (const float*)d_in[4];

    float* hprime = (float*)d_out;                       // 16*64*1024*12
    float* att    = hprime + (size_t)B_SZ * COUT * N_SZ * L_SZ;

    char* ws = (char*)d_ws;
    ushort_t* Xt = (ushort_t*)ws;                              // 25,165,824 B
    ushort_t* Sb = (ushort_t*)(ws + (size_t)25165824);         // 33,554,432 B
    float*    fw = (float*)(ws + (size_t)25165824 + 33554432); //     65,536 B

    conv_mfma_kernel<<<dim3(16, B_SZ), 256, 0, stream>>>(inp, w0, b0, w1, Xt, fw);
    softmax_kernel<<<dim3(N_SZ, B_SZ), 256, 0, stream>>>(adj, fw, Sb);
    att_transpose_kernel<<<dim3(N_SZ / 64, N_SZ / 64, B_SZ), 256, 0, stream>>>(Sb, att);
    gemm2_kernel<<<dim3(CL / 128, N_SZ / 128, B_SZ), 256, 0, stream>>>(Sb, Xt, hprime);
}

// Round 6
// 378.751 us; speedup vs baseline: 1.1987x; 1.1987x over previous
//
#include <hip/hip_runtime.h>
#include <stdint.h>

typedef unsigned short ushort_t;
typedef unsigned int uint_t;

#define B_SZ 16
#define CIN 64
#define COUT 64
#define N_SZ 1024
#define L_SZ 12
#define CL 768            // COUT * L_SZ
#define NL 12288          // N_SZ * L_SZ
#define ALPHA 0.2f

// HARD CONSTRAINT (empirical, rounds 2/3/5): static LDS > 64 KB kills the
// harness container. Every kernel below stays <= 64 KB static LDS.

typedef __bf16 bf16x8 __attribute__((ext_vector_type(8)));
typedef float floatx4 __attribute__((ext_vector_type(4)));
typedef _Float16 half8 __attribute__((ext_vector_type(8)));
typedef _Float16 half4 __attribute__((ext_vector_type(4)));

__device__ __forceinline__ ushort_t f2bf(float x) {
    uint_t u = __float_as_uint(x);
    u += 0x7fffu + ((u >> 16) & 1u);
    return (ushort_t)(u >> 16);
}
__device__ __forceinline__ float bf2f(ushort_t h) {
    return __uint_as_float(((uint_t)h) << 16);
}

// async global->LDS, 16B per lane; LDS dest must be wave-uniform base + lane*16
#define ASYNC16(ldsp, gp)                                                \
    __builtin_amdgcn_global_load_lds(                                    \
        (const __attribute__((address_space(1))) void*)(gp),             \
        (__attribute__((address_space(3))) void*)(ldsp), 16, 0, 0)

// ---------------------------------------------------------------------------
// K1: conv0 (1x3, pad 1) + bias + fused f, f16 MFMA im2col GEMM.
// This is the harness-verified round-4 kernel with ONE change: the output is
// stored in its NATURAL layout Xp[b][co][p=n*12+l] (lanes rr -> consecutive
// p -> contiguous 32B segments), instead of scattered 2B into Xt[m][n].
// R4 counters showed WRITE 140-150MB / FETCH 106MB: 16B-per-128B-line
// partial stores thrashed L2 (evict partial + refetch = HBM RMW). Here each
// block covers 192 consecutive p = 384B = exactly 3 full lines per co-row
// (line-aligned: 192p*2B = 3*128B, so lines are never shared across blocks),
// completed within the block's two back-to-back g-iterations -> no RMW.
// A separate transpose kernel produces Xt[m][n] for gemm2.
// Grid (NL/192=64, B) = 1024 blocks = 4/CU, 16 waves/CU. LDS 38.8 KB.
// ---------------------------------------------------------------------------
__global__ __launch_bounds__(256, 4) void conv_mfma_kernel(
    const float* __restrict__ inp, const float* __restrict__ w0,
    const float* __restrict__ b0, const float* __restrict__ w1,
    ushort_t* __restrict__ Xp, float* __restrict__ fout)
{
    __shared__ _Float16 Bs[96 * 200];   // [p][k 0..191, pad to 200] 38400 B
    __shared__ float fredcol[96];

    const int bx = blockIdx.x;          // 192-p tile (16 n) (0..63)
    const int b  = blockIdx.y;
    const int t  = threadIdx.x;
    const int lane = t & 63, w = t >> 6;     // w = co-tile of this wave
    const int rr = lane & 15, kc = lane >> 4;
    const half4 hz = (half4)(_Float16)0.f;

    if (t < 96) fredcol[t] = 0.f;
    // tile-edge zero columns: written once, never overwritten by staging
    if (t < 16) *(half4*)&Bs[0 * 200 + t * 4] = hz;                    // kt=0, p=0
    else if (t < 32) *(half4*)&Bs[95 * 200 + 128 + (t - 16) * 4] = hz; // kt=2, p=95

    // ---- A fragments (weights) once per block; w0 layout [co][ci][kt] ----
    const int co_r = w * 16 + rr;
    half8 af[6];
#pragma unroll
    for (int ch = 0; ch < 6; ch++) {
        const int kt = ch >> 1;
        const int ci0 = (ch & 1) * 32 + kc * 8;
        const float* wp = w0 + co_r * 192 + ci0 * 3 + kt;
#pragma unroll
        for (int e = 0; e < 8; e++) af[ch][e] = (_Float16)wp[e * 3];
    }

    float b0v[4], w1v[4][12];
#pragma unroll
    for (int r = 0; r < 4; r++) {
        b0v[r] = b0[w * 16 + kc * 4 + r];
#pragma unroll
        for (int l = 0; l < 12; l++) w1v[r][l] = w1[(w * 16 + kc * 4 + r) * 12 + l];
    }

    const float* ibase = inp + (size_t)b * CIN * NL;
    ushort_t* XpB = Xp + (size_t)b * COUT * NL;

#pragma unroll 1
    for (int g = 0; g < 2; g++) {
        const int p0 = bx * 192 + g * 96;

        // ---- stage im2col sub-tile: 1536 tasks = 96 p x 16 ci-groups ----
#pragma unroll
        for (int i = 0; i < 6; i++) {
            const int idx = i * 256 + t;
            const int p = idx % 96;
            const int cig = idx / 96;
            const int l = p % 12;
            const float* src = ibase + (size_t)(cig * 4) * NL + p0 + p;
            half4 hv;
            hv[0] = (_Float16)src[0];
            hv[1] = (_Float16)src[NL];
            hv[2] = (_Float16)src[2 * NL];
            hv[3] = (_Float16)src[3 * NL];
            // kt=1: B[64+ci][p]
            *(half4*)&Bs[p * 200 + 64 + cig * 4] = hv;
            // kt=0: B[ci][p+1], zero across n-row boundary
            if (p + 1 < 96) {
                half4 v0 = hv; if (l == 11) v0 = hz;
                *(half4*)&Bs[(p + 1) * 200 + cig * 4] = v0;
            }
            // kt=2: B[128+ci][p-1], zero across n-row boundary
            if (p >= 1) {
                half4 v2 = hv; if (l == 0) v2 = hz;
                *(half4*)&Bs[(p - 1) * 200 + 128 + cig * 4] = v2;
            }
        }
        __syncthreads();

        // ---- MFMA: 6 p-frags x 6 k-chunks per wave ----
        floatx4 acc[6];
#pragma unroll
        for (int fp = 0; fp < 6; fp++) acc[fp] = (floatx4)0.f;
#pragma unroll
        for (int fp = 0; fp < 6; fp++) {
            const _Float16* brow = &Bs[(fp * 16 + rr) * 200 + kc * 8];
#pragma unroll
            for (int ch = 0; ch < 6; ch++) {
                const half8 bf = *(const half8*)(brow + ch * 32);
                acc[fp] = __builtin_amdgcn_mfma_f32_16x16x32_f16(af[ch], bf, acc[fp], 0, 0, 0);
            }
        }

        // ---- epilogue: bias, Xp bf16 store (contiguous p), partial f ----
#pragma unroll
        for (int fp = 0; fp < 6; fp++) {
            const int pcol = fp * 16 + rr;
            const int pg = p0 + pcol;
            const int l = pcol % 12;          // p0 is a multiple of 12
            float fc = 0.f;
#pragma unroll
            for (int r = 0; r < 4; r++) {
                const int co = w * 16 + kc * 4 + r;
                const float x = acc[fp][r] + b0v[r];
                fc += x * w1v[r][l];
                XpB[(size_t)co * NL + pg] = f2bf(x);   // lanes rr -> contiguous
            }
            atomicAdd(&fredcol[pcol], fc);
        }
        __syncthreads();

        // ---- f for the 8 n of this sub-tile; same threads re-zero ----
        if (t < 8) {
            float s = 0.f;
#pragma unroll
            for (int j = 0; j < 12; j++) s += fredcol[t * 12 + j];
            fout[b * N_SZ + bx * 16 + g * 8 + t] = s;
#pragma unroll
            for (int j = 0; j < 12; j++) fredcol[t * 12 + j] = 0.f;
        }
        // fredcol re-zero is ordered against next g's atomicAdds by next g's
        // stage barrier; Bs overwrite is safe: MFMA reads done before barrier.
    }
}

// ---------------------------------------------------------------------------
// K1b: Xp[b][co][p=n*12+l] -> Xt[b][co*12+l][n]. Per block: one (co,b) pair.
// Read 24KB contiguous (uint4), scatter 2B into LDS [l][n] (row stride 1032
// ushorts: l*516 % 32 = 4l -> banks spread), then write 12 full 2KB rows
// coalesced. All lines on both sides are full -> no RMW anywhere.
// Grid (COUT, B) = 1024 blocks. LDS 24.8 KB.
// ---------------------------------------------------------------------------
__global__ __launch_bounds__(256) void xt_transpose_kernel(
    const ushort_t* __restrict__ Xp, ushort_t* __restrict__ Xt)
{
    __shared__ ushort_t L[12 * 1032];   // [l][n pad 1032] 24768 B
    const int co = blockIdx.x, b = blockIdx.y, t = threadIdx.x;

    const ushort_t* src = Xp + ((size_t)b * COUT + co) * NL;
#pragma unroll
    for (int it = 0; it < 6; it++) {
        const int j = it * 256 + t;                  // uint4 index (0..1535)
        const uint4 v = *(const uint4*)(src + (size_t)j * 8);
        const uint_t wd0 = v.x, wd1 = v.y, wd2 = v.z, wd3 = v.w;
        int n = (j * 8) / 12, l = (j * 8) % 12;
        ushort_t e[8];
        e[0] = (ushort_t)(wd0 & 0xffff); e[1] = (ushort_t)(wd0 >> 16);
        e[2] = (ushort_t)(wd1 & 0xffff); e[3] = (ushort_t)(wd1 >> 16);
        e[4] = (ushort_t)(wd2 & 0xffff); e[5] = (ushort_t)(wd2 >> 16);
        e[6] = (ushort_t)(wd3 & 0xffff); e[7] = (ushort_t)(wd3 >> 16);
#pragma unroll
        for (int k = 0; k < 8; k++) {
            L[l * 1032 + n] = e[k];
            if (++l == 12) { l = 0; ++n; }
        }
    }
    __syncthreads();

    ushort_t* dst = Xt + ((size_t)b * CL + co * 12) * N_SZ;
#pragma unroll
    for (int it = 0; it < 6; it++) {
        const int j = it * 256 + t;                  // 12 l x 128 segs
        const int l = j >> 7, seg = j & 127;
        *(uint4*)&dst[(size_t)l * N_SZ + seg * 8] =
            *(const uint4*)&L[l * 1032 + seg * 8];   // row byte-stride 2064 = 129*16
    }
}

// ---------------------------------------------------------------------------
// K2: z = leaky(f_i + f_j) + adj; row softmax; store S bf16 (row-major).
// Block: 256 thr per row; grid (N, B).
// ---------------------------------------------------------------------------
__global__ __launch_bounds__(256) void softmax_kernel(
    const float* __restrict__ adj, const float* __restrict__ f,
    ushort_t* __restrict__ Sb)
{
    __shared__ float smx[4], sms[4];
    const int i = blockIdx.x, b = blockIdx.y, t = threadIdx.x;
    const int lane = t & 63, wv = t >> 6;

    const float* frow = f + b * N_SZ;
    const float fi = frow[i];
    const float4 fj = *(const float4*)(frow + 4 * t);
    const float4 av = *(const float4*)(adj + ((size_t)b * N_SZ + i) * N_SZ + 4 * t);

    float z[4];
    z[0] = fi + fj.x; z[1] = fi + fj.y; z[2] = fi + fj.z; z[3] = fi + fj.w;
#pragma unroll
    for (int k = 0; k < 4; k++) z[k] = (z[k] >= 0.f) ? z[k] : ALPHA * z[k];
    z[0] += av.x; z[1] += av.y; z[2] += av.z; z[3] += av.w;

    float mx = fmaxf(fmaxf(z[0], z[1]), fmaxf(z[2], z[3]));
#pragma unroll
    for (int o = 32; o; o >>= 1) mx = fmaxf(mx, __shfl_xor(mx, o, 64));
    if (lane == 0) smx[wv] = mx;
    __syncthreads();
    mx = fmaxf(fmaxf(smx[0], smx[1]), fmaxf(smx[2], smx[3]));

    float e[4], s = 0.f;
#pragma unroll
    for (int k = 0; k < 4; k++) { e[k] = __expf(z[k] - mx); s += e[k]; }
#pragma unroll
    for (int o = 32; o; o >>= 1) s += __shfl_xor(s, o, 64);
    if (lane == 0) sms[wv] = s;
    __syncthreads();
    s = sms[0] + sms[1] + sms[2] + sms[3];
    const float inv = 1.0f / s;

    const uint_t p0 = (uint_t)f2bf(e[0] * inv) | ((uint_t)f2bf(e[1] * inv) << 16);
    const uint_t p1 = (uint_t)f2bf(e[2] * inv) | ((uint_t)f2bf(e[3] * inv) << 16);
    uint2 pk; pk.x = p0; pk.y = p1;
    *(uint2*)&Sb[((size_t)b * N_SZ + i) * N_SZ + 4 * t] = pk;
}

// ---------------------------------------------------------------------------
// K3: attention output = S^T, bf16 -> fp32, LDS 64x64 tile transpose.
// grid (N/64, N/64, B): x = i-tile, y = j-tile.
// ---------------------------------------------------------------------------
__global__ __launch_bounds__(256) void att_transpose_kernel(
    const ushort_t* __restrict__ Sb, float* __restrict__ att)
{
    __shared__ float T[64][65];
    const int b = blockIdx.z;
    const int i0 = blockIdx.x * 64, j0 = blockIdx.y * 64;
    const int t = threadIdx.x;

#pragma unroll
    for (int ph = 0; ph < 2; ph++) {
        const int idx = ph * 256 + t;
        const int r = idx >> 3, c8 = (idx & 7) * 8;
        const uint4 v = *(const uint4*)(Sb + ((size_t)b * N_SZ + i0 + r) * N_SZ + j0 + c8);
        T[r][c8 + 0] = bf2f((ushort_t)(v.x & 0xffff));
        T[r][c8 + 1] = bf2f((ushort_t)(v.x >> 16));
        T[r][c8 + 2] = bf2f((ushort_t)(v.y & 0xffff));
        T[r][c8 + 3] = bf2f((ushort_t)(v.y >> 16));
        T[r][c8 + 4] = bf2f((ushort_t)(v.z & 0xffff));
        T[r][c8 + 5] = bf2f((ushort_t)(v.z >> 16));
        T[r][c8 + 6] = bf2f((ushort_t)(v.w & 0xffff));
        T[r][c8 + 7] = bf2f((ushort_t)(v.w >> 16));
    }
    __syncthreads();
#pragma unroll
    for (int ph = 0; ph < 4; ph++) {
        const int idx = ph * 256 + t;
        const int jr = idx >> 4, i4 = (idx & 15) * 4;
        float4 o;
        o.x = T[i4 + 0][jr]; o.y = T[i4 + 1][jr];
        o.z = T[i4 + 2][jr]; o.w = T[i4 + 3][jr];
        *(float4*)(att + ((size_t)b * N_SZ + j0 + jr) * N_SZ + i0 + i4) = o;
    }
}

// ---------------------------------------------------------------------------
// K4: per-batch GEMM  C[q,m] = sum_n S[q,n] * Xt[m,n], m=(co*12+l).
// 128x128 block tile, BK=32, DOUBLE-BUFFERED (T3 minimum-2-phase recipe):
// STAGE(next tile) is issued BEFORE compute(cur); the single __syncthreads
// per K-step provides the vmcnt(0) drain, so global_load_lds latency hides
// under ds_read+MFMA instead of being fully exposed between two barriers
// (the previous serial structure). Fragment indexing identical to the
// verified kernel. LDS 2 x 16 KB = 32 KB. grid (CL/128=6, N/128=8, B).
// ---------------------------------------------------------------------------
__global__ __launch_bounds__(256) void gemm2_kernel(
    const ushort_t* __restrict__ Sb, const ushort_t* __restrict__ Xt,
    float* __restrict__ out)
{
    __shared__ ushort_t As[2][512 * 8];
    __shared__ ushort_t Bs[2][512 * 8];
    const int b = blockIdx.z;
    const int m0 = blockIdx.x * 128, q0 = blockIdx.y * 128;
    const int t = threadIdx.x;
    const int lane = t & 63, wv = t >> 6;
    const int wq = wv >> 1, wm = wv & 1;
    const int kc = lane >> 4, rr = lane & 15;

    const ushort_t* Sbase = Sb + (size_t)b * N_SZ * N_SZ;
    const ushort_t* Xbase = Xt + (size_t)b * CL * N_SZ;

#define G2STAGE(bb, k0)                                                      \
    do {                                                                     \
        _Pragma("unroll")                                                    \
        for (int c = 0; c < 2; c++) {                                        \
            const int u = c * 256 + t;                                       \
            const int r = u & 127, kcs = u >> 7;                             \
            ASYNC16(&As[bb][u * 8], Sbase + (size_t)(q0 + r) * N_SZ + (k0) + kcs * 8); \
            ASYNC16(&Bs[bb][u * 8], Xbase + (size_t)(m0 + r) * N_SZ + (k0) + kcs * 8); \
        }                                                                    \
    } while (0)

    floatx4 acc[4][4];
#pragma unroll
    for (int i = 0; i < 4; i++)
#pragma unroll
        for (int j = 0; j < 4; j++) acc[i][j] = (floatx4)0.f;

    G2STAGE(0, 0);
    __syncthreads();                 // compiler emits vmcnt(0) drain here

    int cur = 0;
#pragma unroll 1
    for (int kt = 0; kt < 31; kt++) {
        G2STAGE(cur ^ 1, (kt + 1) * 32);   // next tile in flight during compute

        bf16x8 af[4], bfr[4];
#pragma unroll
        for (int i = 0; i < 4; i++) {
            af[i]  = *(const bf16x8*)&As[cur][(kc * 128 + wq * 64 + i * 16 + rr) * 8];
            bfr[i] = *(const bf16x8*)&Bs[cur][(kc * 128 + wm * 64 + i * 16 + rr) * 8];
        }
#pragma unroll
        for (int i = 0; i < 4; i++)
#pragma unroll
            for (int j = 0; j < 4; j++)
                acc[i][j] = __builtin_amdgcn_mfma_f32_16x16x32_bf16(
                    af[i], bfr[j], acc[i][j], 0, 0, 0);

        __syncthreads();             // drains staging; releases both buffers
        cur ^= 1;
    }
    {   // last tile (kt = 31), already resident in buf[cur]
        bf16x8 af[4], bfr[4];
#pragma unroll
        for (int i = 0; i < 4; i++) {
            af[i]  = *(const bf16x8*)&As[cur][(kc * 128 + wq * 64 + i * 16 + rr) * 8];
            bfr[i] = *(const bf16x8*)&Bs[cur][(kc * 128 + wm * 64 + i * 16 + rr) * 8];
        }
#pragma unroll
        for (int i = 0; i < 4; i++)
#pragma unroll
            for (int j = 0; j < 4; j++)
                acc[i][j] = __builtin_amdgcn_mfma_f32_16x16x32_bf16(
                    af[i], bfr[j], acc[i][j], 0, 0, 0);
    }
#undef G2STAGE

    // epilogue: C row = q (= kc*4 + reg within frag), col = m (= rr within frag)
#pragma unroll
    for (int j = 0; j < 4; j++) {
        const int m = m0 + wm * 64 + j * 16 + rr;
        const int co = m / 12, l = m - co * 12;
        float* ob = out + (size_t)(b * COUT + co) * (N_SZ * L_SZ) + l;
#pragma unroll
        for (int i = 0; i < 4; i++) {
            const int q = q0 + wq * 64 + i * 16 + kc * 4;
#pragma unroll
            for (int r2 = 0; r2 < 4; r2++)
                ob[(size_t)(q + r2) * 12] = acc[i][j][r2];
        }
    }
}

// ---------------------------------------------------------------------------
extern "C" void kernel_launch(void* const* d_in, const int* in_sizes, int n_in,
                              void* d_out, int out_size, void* d_ws, size_t ws_size,
                              hipStream_t stream)
{
    const float* inp = (const float*)d_in[0];
    const float* adj = (const float*)d_in[1];
    const float* w0  = (const float*)d_in[2];
    const float* b0  = (const float*)d_in[3];
    const float* w1  = (const float*)d_in[4];

    float* hprime = (float*)d_out;                       // 16*64*1024*12 fp32
    float* att    = hprime + (size_t)B_SZ * COUT * N_SZ * L_SZ;  // 16*1024*1024 fp32

    char* ws = (char*)d_ws;
    ushort_t* Xt = (ushort_t*)ws;                              // 25,165,824 B
    ushort_t* Sb = (ushort_t*)(ws + (size_t)25165824);         // 33,554,432 B
    float*    fw = (float*)(ws + (size_t)25165824 + 33554432); //     65,536 B

    // Xp (conv's natural-layout output, 25.2 MB) lives in the att region of
    // d_out: it is consumed by xt_transpose BEFORE att_transpose overwrites
    // the region later in the stream. Zero workspace growth.
    ushort_t* Xp = (ushort_t*)att;

    conv_mfma_kernel<<<dim3(64, B_SZ), 256, 0, stream>>>(inp, w0, b0, w1, Xp, fw);
    xt_transpose_kernel<<<dim3(COUT, B_SZ), 256, 0, stream>>>(Xp, Xt);
    softmax_kernel<<<dim3(N_SZ, B_SZ), 256, 0, stream>>>(adj, fw, Sb);
    att_transpose_kernel<<<dim3(N_SZ / 64, N_SZ / 64, B_SZ), 256, 0, stream>>>(Sb, att);
    gemm2_kernel<<<dim3(CL / 128, N_SZ / 128, B_SZ), 256, 0, stream>>>(Sb, Xt, hprime);
}

// Round 7
// 342.213 us; speedup vs baseline: 1.3267x; 1.1068x over previous
//
#include <hip/hip_runtime.h>
#include <stdint.h>

typedef unsigned short ushort_t;
typedef unsigned int uint_t;

#define B_SZ 16
#define CIN 64
#define COUT 64
#define N_SZ 1024
#define L_SZ 12
#define CL 768            // COUT * L_SZ
#define NL 12288          // N_SZ * L_SZ
#define ALPHA 0.2f

// HARD CONSTRAINT (confirmed mechanism): hipcc static __shared__ limit is
// 64 KB; rounds 2/3/5 (77.8/149 KB) were compile failures surfacing as
// container crashes. Every kernel stays <= 64 KB static LDS.

typedef __bf16 bf16x8 __attribute__((ext_vector_type(8)));
typedef float floatx4 __attribute__((ext_vector_type(4)));
typedef _Float16 half8 __attribute__((ext_vector_type(8)));
typedef _Float16 half4 __attribute__((ext_vector_type(4)));

__device__ __forceinline__ ushort_t f2bf(float x) {
    uint_t u = __float_as_uint(x);
    u += 0x7fffu + ((u >> 16) & 1u);
    return (ushort_t)(u >> 16);
}
__device__ __forceinline__ float bf2f(ushort_t h) {
    return __uint_as_float(((uint_t)h) << 16);
}

// async global->LDS, 16B per lane; LDS dest must be wave-uniform base + lane*16
#define ASYNC16(ldsp, gp)                                                \
    __builtin_amdgcn_global_load_lds(                                    \
        (const __attribute__((address_space(1))) void*)(gp),             \
        (__attribute__((address_space(3))) void*)(ldsp), 16, 0, 0)

// ---------------------------------------------------------------------------
// K0: pack w0[co][ci][kt] f32 -> wt[co][kt][ci] f16 (24 KB). Run once per
// launch; makes conv's A-fragment load 6 contiguous 16B loads per thread
// instead of 48 scattered stride-12B dwords (R6 FETCH suspect #1).
// ---------------------------------------------------------------------------
__global__ __launch_bounds__(256) void prep_w_kernel(
    const float* __restrict__ w0, _Float16* __restrict__ wt)
{
    const int t = threadIdx.x;
#pragma unroll
    for (int it = 0; it < 48; it++) {
        const int j = it * 256 + t;           // 12288 elements
        const int co = j / 192, rem = j - co * 192;
        const int kt = rem >> 6, ci = rem & 63;
        wt[j] = (_Float16)w0[co * 192 + ci * 3 + kt];
    }
}

// ---------------------------------------------------------------------------
// K1: conv0 (1x3, pad 1) + bias + fused f, f16 MFMA im2col GEMM.
// R6 counters: dur 107us, WRITE 77MB (3x ideal), FETCH 257MB (5x input).
// Round-7 fixes (staging/MFMA core identical to the verified R6 kernel):
//  (a) A-fragments from pre-packed wt[co][kt][ci] f16: 6 x 16B contiguous
//      loads/thread (was 48 scattered dwords, ~64 lines per instruction,
//      up to 48KB x 1024 blocks of L2-cold refetch).
//  (b) Xp stores buffered in LDS Xob[64 co][192 p] across both g-iterations,
//      then one writeout pass: each co row = 384B = 3 exactly-aligned FULL
//      128B lines, uint4 stores, each line written once complete -> no RFO
//      fetch, no partial-line multi-flush (R6's WRITE 3x + FETCH residue).
// LDS = 38400 (Bs) + 25600 (Xob, rows padded to 200 ushorts) + 384 = 64384 B
// <= 64KB. 2 blocks/CU. Grid (NL/192=64, B) = 1024 blocks.
// ---------------------------------------------------------------------------
__global__ __launch_bounds__(256) void conv_mfma_kernel(
    const float* __restrict__ inp, const _Float16* __restrict__ wt,
    const float* __restrict__ b0, const float* __restrict__ w1,
    ushort_t* __restrict__ Xp, float* __restrict__ fout)
{
    __shared__ _Float16 Bs[96 * 200];     // [p][k 0..191, pad 200] 38400 B
    __shared__ ushort_t Xob[64 * 200];    // [co][p 0..191, pad 200] 25600 B
    __shared__ float fredcol[96];

    const int bx = blockIdx.x;          // 192-p tile (16 n) (0..63)
    const int b  = blockIdx.y;
    const int t  = threadIdx.x;
    const int lane = t & 63, w = t >> 6;     // w = co-tile of this wave
    const int rr = lane & 15, kc = lane >> 4;
    const half4 hz = (half4)(_Float16)0.f;

    if (t < 96) fredcol[t] = 0.f;
    // tile-edge zero columns: written once, never overwritten by staging
    if (t < 16) *(half4*)&Bs[0 * 200 + t * 4] = hz;                    // kt=0, p=0
    else if (t < 32) *(half4*)&Bs[95 * 200 + 128 + (t - 16) * 4] = hz; // kt=2, p=95

    // ---- A fragments from packed wt: 6 contiguous 16B loads ----
    const int co_r = w * 16 + rr;
    half8 af[6];
#pragma unroll
    for (int ch = 0; ch < 6; ch++) {
        const int kt = ch >> 1;
        const int ci0 = (ch & 1) * 32 + kc * 8;
        af[ch] = *(const half8*)(wt + co_r * 192 + kt * 64 + ci0);
    }

    float b0v[4], w1v[4][12];
#pragma unroll
    for (int r = 0; r < 4; r++) {
        b0v[r] = b0[w * 16 + kc * 4 + r];
#pragma unroll
        for (int l = 0; l < 12; l++) w1v[r][l] = w1[(w * 16 + kc * 4 + r) * 12 + l];
    }

    const float* ibase = inp + (size_t)b * CIN * NL;

#pragma unroll 1
    for (int g = 0; g < 2; g++) {
        const int p0 = bx * 192 + g * 96;

        // ---- stage im2col sub-tile: 1536 tasks = 96 p x 16 ci-groups ----
#pragma unroll
        for (int i = 0; i < 6; i++) {
            const int idx = i * 256 + t;
            const int p = idx % 96;
            const int cig = idx / 96;
            const int l = p % 12;
            const float* src = ibase + (size_t)(cig * 4) * NL + p0 + p;
            half4 hv;
            hv[0] = (_Float16)src[0];
            hv[1] = (_Float16)src[NL];
            hv[2] = (_Float16)src[2 * NL];
            hv[3] = (_Float16)src[3 * NL];
            // kt=1: B[64+ci][p]
            *(half4*)&Bs[p * 200 + 64 + cig * 4] = hv;
            // kt=0: B[ci][p+1], zero across n-row boundary
            if (p + 1 < 96) {
                half4 v0 = hv; if (l == 11) v0 = hz;
                *(half4*)&Bs[(p + 1) * 200 + cig * 4] = v0;
            }
            // kt=2: B[128+ci][p-1], zero across n-row boundary
            if (p >= 1) {
                half4 v2 = hv; if (l == 0) v2 = hz;
                *(half4*)&Bs[(p - 1) * 200 + 128 + cig * 4] = v2;
            }
        }
        __syncthreads();

        // ---- MFMA: 6 p-frags x 6 k-chunks per wave ----
        floatx4 acc[6];
#pragma unroll
        for (int fp = 0; fp < 6; fp++) acc[fp] = (floatx4)0.f;
#pragma unroll
        for (int fp = 0; fp < 6; fp++) {
            const _Float16* brow = &Bs[(fp * 16 + rr) * 200 + kc * 8];
#pragma unroll
            for (int ch = 0; ch < 6; ch++) {
                const half8 bf = *(const half8*)(brow + ch * 32);
                acc[fp] = __builtin_amdgcn_mfma_f32_16x16x32_f16(af[ch], bf, acc[fp], 0, 0, 0);
            }
        }

        // ---- epilogue: bias, bf16 -> Xob (LDS), partial f ----
#pragma unroll
        for (int fp = 0; fp < 6; fp++) {
            const int pcol = fp * 16 + rr;
            const int l = pcol % 12;          // p0 is a multiple of 12
            float fc = 0.f;
#pragma unroll
            for (int r = 0; r < 4; r++) {
                const int co = w * 16 + kc * 4 + r;
                const float x = acc[fp][r] + b0v[r];
                fc += x * w1v[r][l];
                Xob[co * 200 + g * 96 + pcol] = f2bf(x);
            }
            atomicAdd(&fredcol[pcol], fc);
        }
        __syncthreads();

        // ---- f for the 8 n of this sub-tile; same threads re-zero ----
        if (t < 8) {
            float s = 0.f;
#pragma unroll
            for (int j = 0; j < 12; j++) s += fredcol[t * 12 + j];
            fout[b * N_SZ + bx * 16 + g * 8 + t] = s;
#pragma unroll
            for (int j = 0; j < 12; j++) fredcol[t * 12 + j] = 0.f;
        }
        // Bs overwrite next g is safe (MFMA reads done before the barrier);
        // fredcol re-zero is ordered by next g's stage barrier.
    }

    // ---- writeout: Xob -> Xp, full 128B lines only ----
    // 1536 tasks = 64 co-rows x 24 uint4 segs; each co row = 384B = 3 full
    // aligned lines (co*NL*2 and bx*384 are 128B multiples), written once.
    // All Xob writes visible: g-loop ended with __syncthreads.
    ushort_t* XpB = Xp + (size_t)b * COUT * NL + bx * 192;
#pragma unroll
    for (int it = 0; it < 6; it++) {
        const int idx = it * 256 + t;
        const int row = idx / 24, seg = idx - row * 24;
        *(uint4*)(XpB + (size_t)row * NL + seg * 8) =
            *(const uint4*)&Xob[row * 200 + seg * 8];
    }
}

// ---------------------------------------------------------------------------
// K1b: Xp[b][co][p=n*12+l] -> Xt[b][co*12+l][n]. Per block: one (co,b) pair.
// Read 24KB contiguous (uint4), scatter 2B into LDS [l][n] (row stride 1032
// ushorts), then write 12 full 2KB rows coalesced. Full lines both sides.
// Grid (COUT, B) = 1024 blocks. LDS 24.8 KB.
// ---------------------------------------------------------------------------
__global__ __launch_bounds__(256) void xt_transpose_kernel(
    const ushort_t* __restrict__ Xp, ushort_t* __restrict__ Xt)
{
    __shared__ ushort_t L[12 * 1032];   // [l][n pad 1032] 24768 B
    const int co = blockIdx.x, b = blockIdx.y, t = threadIdx.x;

    const ushort_t* src = Xp + ((size_t)b * COUT + co) * NL;
#pragma unroll
    for (int it = 0; it < 6; it++) {
        const int j = it * 256 + t;                  // uint4 index (0..1535)
        const uint4 v = *(const uint4*)(src + (size_t)j * 8);
        const uint_t wd0 = v.x, wd1 = v.y, wd2 = v.z, wd3 = v.w;
        int n = (j * 8) / 12, l = (j * 8) % 12;
        ushort_t e[8];
        e[0] = (ushort_t)(wd0 & 0xffff); e[1] = (ushort_t)(wd0 >> 16);
        e[2] = (ushort_t)(wd1 & 0xffff); e[3] = (ushort_t)(wd1 >> 16);
        e[4] = (ushort_t)(wd2 & 0xffff); e[5] = (ushort_t)(wd2 >> 16);
        e[6] = (ushort_t)(wd3 & 0xffff); e[7] = (ushort_t)(wd3 >> 16);
#pragma unroll
        for (int k = 0; k < 8; k++) {
            L[l * 1032 + n] = e[k];
            if (++l == 12) { l = 0; ++n; }
        }
    }
    __syncthreads();

    ushort_t* dst = Xt + ((size_t)b * CL + co * 12) * N_SZ;
#pragma unroll
    for (int it = 0; it < 6; it++) {
        const int j = it * 256 + t;                  // 12 l x 128 segs
        const int l = j >> 7, seg = j & 127;
        *(uint4*)&dst[(size_t)l * N_SZ + seg * 8] =
            *(const uint4*)&L[l * 1032 + seg * 8];
    }
}

// ---------------------------------------------------------------------------
// K2: z = leaky(f_i + f_j) + adj; row softmax; store S bf16 (row-major).
// Block: 256 thr per row; grid (N, B).
// ---------------------------------------------------------------------------
__global__ __launch_bounds__(256) void softmax_kernel(
    const float* __restrict__ adj, const float* __restrict__ f,
    ushort_t* __restrict__ Sb)
{
    __shared__ float smx[4], sms[4];
    const int i = blockIdx.x, b = blockIdx.y, t = threadIdx.x;
    const int lane = t & 63, wv = t >> 6;

    const float* frow = f + b * N_SZ;
    const float fi = frow[i];
    const float4 fj = *(const float4*)(frow + 4 * t);
    const float4 av = *(const float4*)(adj + ((size_t)b * N_SZ + i) * N_SZ + 4 * t);

    float z[4];
    z[0] = fi + fj.x; z[1] = fi + fj.y; z[2] = fi + fj.z; z[3] = fi + fj.w;
#pragma unroll
    for (int k = 0; k < 4; k++) z[k] = (z[k] >= 0.f) ? z[k] : ALPHA * z[k];
    z[0] += av.x; z[1] += av.y; z[2] += av.z; z[3] += av.w;

    float mx = fmaxf(fmaxf(z[0], z[1]), fmaxf(z[2], z[3]));
#pragma unroll
    for (int o = 32; o; o >>= 1) mx = fmaxf(mx, __shfl_xor(mx, o, 64));
    if (lane == 0) smx[wv] = mx;
    __syncthreads();
    mx = fmaxf(fmaxf(smx[0], smx[1]), fmaxf(smx[2], smx[3]));

    float e[4], s = 0.f;
#pragma unroll
    for (int k = 0; k < 4; k++) { e[k] = __expf(z[k] - mx); s += e[k]; }
#pragma unroll
    for (int o = 32; o; o >>= 1) s += __shfl_xor(s, o, 64);
    if (lane == 0) sms[wv] = s;
    __syncthreads();
    s = sms[0] + sms[1] + sms[2] + sms[3];
    const float inv = 1.0f / s;

    const uint_t p0 = (uint_t)f2bf(e[0] * inv) | ((uint_t)f2bf(e[1] * inv) << 16);
    const uint_t p1 = (uint_t)f2bf(e[2] * inv) | ((uint_t)f2bf(e[3] * inv) << 16);
    uint2 pk; pk.x = p0; pk.y = p1;
    *(uint2*)&Sb[((size_t)b * N_SZ + i) * N_SZ + 4 * t] = pk;
}

// ---------------------------------------------------------------------------
// K3: attention output = S^T, bf16 -> fp32, LDS 64x64 tile transpose.
// grid (N/64, N/64, B): x = i-tile, y = j-tile.
// ---------------------------------------------------------------------------
__global__ __launch_bounds__(256) void att_transpose_kernel(
    const ushort_t* __restrict__ Sb, float* __restrict__ att)
{
    __shared__ float T[64][65];
    const int b = blockIdx.z;
    const int i0 = blockIdx.x * 64, j0 = blockIdx.y * 64;
    const int t = threadIdx.x;

#pragma unroll
    for (int ph = 0; ph < 2; ph++) {
        const int idx = ph * 256 + t;
        const int r = idx >> 3, c8 = (idx & 7) * 8;
        const uint4 v = *(const uint4*)(Sb + ((size_t)b * N_SZ + i0 + r) * N_SZ + j0 + c8);
        T[r][c8 + 0] = bf2f((ushort_t)(v.x & 0xffff));
        T[r][c8 + 1] = bf2f((ushort_t)(v.x >> 16));
        T[r][c8 + 2] = bf2f((ushort_t)(v.y & 0xffff));
        T[r][c8 + 3] = bf2f((ushort_t)(v.y >> 16));
        T[r][c8 + 4] = bf2f((ushort_t)(v.z & 0xffff));
        T[r][c8 + 5] = bf2f((ushort_t)(v.z >> 16));
        T[r][c8 + 6] = bf2f((ushort_t)(v.w & 0xffff));
        T[r][c8 + 7] = bf2f((ushort_t)(v.w >> 16));
    }
    __syncthreads();
#pragma unroll
    for (int ph = 0; ph < 4; ph++) {
        const int idx = ph * 256 + t;
        const int jr = idx >> 4, i4 = (idx & 15) * 4;
        float4 o;
        o.x = T[i4 + 0][jr]; o.y = T[i4 + 1][jr];
        o.z = T[i4 + 2][jr]; o.w = T[i4 + 3][jr];
        *(float4*)(att + ((size_t)b * N_SZ + j0 + jr) * N_SZ + i0 + i4) = o;
    }
}

// ---------------------------------------------------------------------------
// K4: per-batch GEMM  C[q,m] = sum_n S[q,n] * Xt[m,n], m=(co*12+l).
// 128x128 block tile, BK=32, double-buffered (T3 minimum-2-phase):
// STAGE(next) issued before compute(cur); one __syncthreads per K-step.
// LDS 2 x 16 KB = 32 KB. grid (CL/128=6, N/128=8, B).
// ---------------------------------------------------------------------------
__global__ __launch_bounds__(256) void gemm2_kernel(
    const ushort_t* __restrict__ Sb, const ushort_t* __restrict__ Xt,
    float* __restrict__ out)
{
    __shared__ ushort_t As[2][512 * 8];
    __shared__ ushort_t Bs[2][512 * 8];
    const int b = blockIdx.z;
    const int m0 = blockIdx.x * 128, q0 = blockIdx.y * 128;
    const int t = threadIdx.x;
    const int lane = t & 63, wv = t >> 6;
    const int wq = wv >> 1, wm = wv & 1;
    const int kc = lane >> 4, rr = lane & 15;

    const ushort_t* Sbase = Sb + (size_t)b * N_SZ * N_SZ;
    const ushort_t* Xbase = Xt + (size_t)b * CL * N_SZ;

#define G2STAGE(bb, k0)                                                      \
    do {                                                                     \
        _Pragma("unroll")                                                    \
        for (int c = 0; c < 2; c++) {                                        \
            const int u = c * 256 + t;                                       \
            const int r = u & 127, kcs = u >> 7;                             \
            ASYNC16(&As[bb][u * 8], Sbase + (size_t)(q0 + r) * N_SZ + (k0) + kcs * 8); \
            ASYNC16(&Bs[bb][u * 8], Xbase + (size_t)(m0 + r) * N_SZ + (k0) + kcs * 8); \
        }                                                                    \
    } while (0)

    floatx4 acc[4][4];
#pragma unroll
    for (int i = 0; i < 4; i++)
#pragma unroll
        for (int j = 0; j < 4; j++) acc[i][j] = (floatx4)0.f;

    G2STAGE(0, 0);
    __syncthreads();

    int cur = 0;
#pragma unroll 1
    for (int kt = 0; kt < 31; kt++) {
        G2STAGE(cur ^ 1, (kt + 1) * 32);

        bf16x8 af[4], bfr[4];
#pragma unroll
        for (int i = 0; i < 4; i++) {
            af[i]  = *(const bf16x8*)&As[cur][(kc * 128 + wq * 64 + i * 16 + rr) * 8];
            bfr[i] = *(const bf16x8*)&Bs[cur][(kc * 128 + wm * 64 + i * 16 + rr) * 8];
        }
#pragma unroll
        for (int i = 0; i < 4; i++)
#pragma unroll
            for (int j = 0; j < 4; j++)
                acc[i][j] = __builtin_amdgcn_mfma_f32_16x16x32_bf16(
                    af[i], bfr[j], acc[i][j], 0, 0, 0);

        __syncthreads();
        cur ^= 1;
    }
    {   // last tile (kt = 31)
        bf16x8 af[4], bfr[4];
#pragma unroll
        for (int i = 0; i < 4; i++) {
            af[i]  = *(const bf16x8*)&As[cur][(kc * 128 + wq * 64 + i * 16 + rr) * 8];
            bfr[i] = *(const bf16x8*)&Bs[cur][(kc * 128 + wm * 64 + i * 16 + rr) * 8];
        }
#pragma unroll
        for (int i = 0; i < 4; i++)
#pragma unroll
            for (int j = 0; j < 4; j++)
                acc[i][j] = __builtin_amdgcn_mfma_f32_16x16x32_bf16(
                    af[i], bfr[j], acc[i][j], 0, 0, 0);
    }
#undef G2STAGE

    // epilogue: C row = q (= kc*4 + reg within frag), col = m (= rr within frag)
#pragma unroll
    for (int j = 0; j < 4; j++) {
        const int m = m0 + wm * 64 + j * 16 + rr;
        const int co = m / 12, l = m - co * 12;
        float* ob = out + (size_t)(b * COUT + co) * (N_SZ * L_SZ) + l;
#pragma unroll
        for (int i = 0; i < 4; i++) {
            const int q = q0 + wq * 64 + i * 16 + kc * 4;
#pragma unroll
            for (int r2 = 0; r2 < 4; r2++)
                ob[(size_t)(q + r2) * 12] = acc[i][j][r2];
        }
    }
}

// ---------------------------------------------------------------------------
extern "C" void kernel_launch(void* const* d_in, const int* in_sizes, int n_in,
                              void* d_out, int out_size, void* d_ws, size_t ws_size,
                              hipStream_t stream)
{
    const float* inp = (const float*)d_in[0];
    const float* adj = (const float*)d_in[1];
    const float* w0  = (const float*)d_in[2];
    const float* b0  = (const float*)d_in[3];
    const float* w1  = (const float*)d_in[4];

    float* hprime = (float*)d_out;                       // 16*64*1024*12 fp32
    float* att    = hprime + (size_t)B_SZ * COUT * N_SZ * L_SZ;  // 64 MB region

    char* ws = (char*)d_ws;
    ushort_t* Xt = (ushort_t*)ws;                              // 25,165,824 B
    ushort_t* Sb = (ushort_t*)(ws + (size_t)25165824);         // 33,554,432 B
    float*    fw = (float*)(ws + (size_t)25165824 + 33554432); //     65,536 B

    // Scratch overlaid on the att region of d_out (consumed before
    // att_transpose overwrites it): Xp at offset 0 (25.2 MB), wt at +32 MB.
    ushort_t* Xp = (ushort_t*)att;
    _Float16* wt = (_Float16*)((char*)att + 33554432);         //     24,576 B

    prep_w_kernel<<<dim3(1), 256, 0, stream>>>(w0, wt);
    conv_mfma_kernel<<<dim3(64, B_SZ), 256, 0, stream>>>(inp, wt, b0, w1, Xp, fw);
    xt_transpose_kernel<<<dim3(COUT, B_SZ), 256, 0, stream>>>(Xp, Xt);
    softmax_kernel<<<dim3(N_SZ, B_SZ), 256, 0, stream>>>(adj, fw, Sb);
    att_transpose_kernel<<<dim3(N_SZ / 64, N_SZ / 64, B_SZ), 256, 0, stream>>>(Sb, att);
    gemm2_kernel<<<dim3(CL / 128, N_SZ / 128, B_SZ), 256, 0, stream>>>(Sb, Xt, hprime);
}

// Round 8
// 335.677 us; speedup vs baseline: 1.3525x; 1.0195x over previous
//
#include <hip/hip_runtime.h>
#include <stdint.h>

typedef unsigned short ushort_t;
typedef unsigned int uint_t;

#define B_SZ 16
#define CIN 64
#define COUT 64
#define N_SZ 1024
#define L_SZ 12
#define CL 768            // COUT * L_SZ
#define NL 12288          // N_SZ * L_SZ
#define ALPHA 0.2f

// HARD CONSTRAINT (confirmed): static __shared__ must stay <= 64 KB
// (rounds 2/3/5 with 77.8/149 KB failed the toolchain/container).

typedef __bf16 bf16x8 __attribute__((ext_vector_type(8)));
typedef float floatx4 __attribute__((ext_vector_type(4)));
typedef _Float16 half8 __attribute__((ext_vector_type(8)));
typedef _Float16 half4 __attribute__((ext_vector_type(4)));

__device__ __forceinline__ ushort_t f2bf(float x) {
    uint_t u = __float_as_uint(x);
    u += 0x7fffu + ((u >> 16) & 1u);
    return (ushort_t)(u >> 16);
}
__device__ __forceinline__ float bf2f(ushort_t h) {
    return __uint_as_float(((uint_t)h) << 16);
}

// async global->LDS, 16B per lane; LDS dest must be wave-uniform base + lane*16
#define ASYNC16(ldsp, gp)                                                \
    __builtin_amdgcn_global_load_lds(                                    \
        (const __attribute__((address_space(1))) void*)(gp),             \
        (__attribute__((address_space(3))) void*)(ldsp), 16, 0, 0)

// ---------------------------------------------------------------------------
// K0: pack w0[co][ci][kt] f32 -> wt[co][kt][ci] f16 (24 KB). Run once.
// ---------------------------------------------------------------------------
__global__ __launch_bounds__(256) void prep_w_kernel(
    const float* __restrict__ w0, _Float16* __restrict__ wt)
{
    const int t = threadIdx.x;
#pragma unroll
    for (int it = 0; it < 48; it++) {
        const int j = it * 256 + t;           // 12288 elements
        const int co = j / 192, rem = j - co * 192;
        const int kt = rem >> 6, ci = rem & 63;
        wt[j] = (_Float16)w0[co * 192 + ci * 3 + kt];
    }
}

// ---------------------------------------------------------------------------
// K1: conv0 (1x3, pad 1) + bias + fused f, f16 MFMA im2col GEMM.
// (Unchanged from round 7 — verified; dropped out of top-5 at <78us.)
// ---------------------------------------------------------------------------
__global__ __launch_bounds__(256) void conv_mfma_kernel(
    const float* __restrict__ inp, const _Float16* __restrict__ wt,
    const float* __restrict__ b0, const float* __restrict__ w1,
    ushort_t* __restrict__ Xp, float* __restrict__ fout)
{
    __shared__ _Float16 Bs[96 * 200];     // [p][k 0..191, pad 200] 38400 B
    __shared__ ushort_t Xob[64 * 200];    // [co][p 0..191, pad 200] 25600 B
    __shared__ float fredcol[96];

    const int bx = blockIdx.x;          // 192-p tile (16 n) (0..63)
    const int b  = blockIdx.y;
    const int t  = threadIdx.x;
    const int lane = t & 63, w = t >> 6;     // w = co-tile of this wave
    const int rr = lane & 15, kc = lane >> 4;
    const half4 hz = (half4)(_Float16)0.f;

    if (t < 96) fredcol[t] = 0.f;
    if (t < 16) *(half4*)&Bs[0 * 200 + t * 4] = hz;                    // kt=0, p=0
    else if (t < 32) *(half4*)&Bs[95 * 200 + 128 + (t - 16) * 4] = hz; // kt=2, p=95

    // ---- A fragments from packed wt: 6 contiguous 16B loads ----
    const int co_r = w * 16 + rr;
    half8 af[6];
#pragma unroll
    for (int ch = 0; ch < 6; ch++) {
        const int kt = ch >> 1;
        const int ci0 = (ch & 1) * 32 + kc * 8;
        af[ch] = *(const half8*)(wt + co_r * 192 + kt * 64 + ci0);
    }

    float b0v[4], w1v[4][12];
#pragma unroll
    for (int r = 0; r < 4; r++) {
        b0v[r] = b0[w * 16 + kc * 4 + r];
#pragma unroll
        for (int l = 0; l < 12; l++) w1v[r][l] = w1[(w * 16 + kc * 4 + r) * 12 + l];
    }

    const float* ibase = inp + (size_t)b * CIN * NL;

#pragma unroll 1
    for (int g = 0; g < 2; g++) {
        const int p0 = bx * 192 + g * 96;

        // ---- stage im2col sub-tile: 1536 tasks = 96 p x 16 ci-groups ----
#pragma unroll
        for (int i = 0; i < 6; i++) {
            const int idx = i * 256 + t;
            const int p = idx % 96;
            const int cig = idx / 96;
            const int l = p % 12;
            const float* src = ibase + (size_t)(cig * 4) * NL + p0 + p;
            half4 hv;
            hv[0] = (_Float16)src[0];
            hv[1] = (_Float16)src[NL];
            hv[2] = (_Float16)src[2 * NL];
            hv[3] = (_Float16)src[3 * NL];
            // kt=1: B[64+ci][p]
            *(half4*)&Bs[p * 200 + 64 + cig * 4] = hv;
            // kt=0: B[ci][p+1], zero across n-row boundary
            if (p + 1 < 96) {
                half4 v0 = hv; if (l == 11) v0 = hz;
                *(half4*)&Bs[(p + 1) * 200 + cig * 4] = v0;
            }
            // kt=2: B[128+ci][p-1], zero across n-row boundary
            if (p >= 1) {
                half4 v2 = hv; if (l == 0) v2 = hz;
                *(half4*)&Bs[(p - 1) * 200 + 128 + cig * 4] = v2;
            }
        }
        __syncthreads();

        // ---- MFMA: 6 p-frags x 6 k-chunks per wave ----
        floatx4 acc[6];
#pragma unroll
        for (int fp = 0; fp < 6; fp++) acc[fp] = (floatx4)0.f;
#pragma unroll
        for (int fp = 0; fp < 6; fp++) {
            const _Float16* brow = &Bs[(fp * 16 + rr) * 200 + kc * 8];
#pragma unroll
            for (int ch = 0; ch < 6; ch++) {
                const half8 bf = *(const half8*)(brow + ch * 32);
                acc[fp] = __builtin_amdgcn_mfma_f32_16x16x32_f16(af[ch], bf, acc[fp], 0, 0, 0);
            }
        }

        // ---- epilogue: bias, bf16 -> Xob (LDS), partial f ----
#pragma unroll
        for (int fp = 0; fp < 6; fp++) {
            const int pcol = fp * 16 + rr;
            const int l = pcol % 12;          // p0 is a multiple of 12
            float fc = 0.f;
#pragma unroll
            for (int r = 0; r < 4; r++) {
                const int co = w * 16 + kc * 4 + r;
                const float x = acc[fp][r] + b0v[r];
                fc += x * w1v[r][l];
                Xob[co * 200 + g * 96 + pcol] = f2bf(x);
            }
            atomicAdd(&fredcol[pcol], fc);
        }
        __syncthreads();

        // ---- f for the 8 n of this sub-tile; same threads re-zero ----
        if (t < 8) {
            float s = 0.f;
#pragma unroll
            for (int j = 0; j < 12; j++) s += fredcol[t * 12 + j];
            fout[b * N_SZ + bx * 16 + g * 8 + t] = s;
#pragma unroll
            for (int j = 0; j < 12; j++) fredcol[t * 12 + j] = 0.f;
        }
    }

    // ---- writeout: Xob -> Xp, full 128B lines only ----
    ushort_t* XpB = Xp + (size_t)b * COUT * NL + bx * 192;
#pragma unroll
    for (int it = 0; it < 6; it++) {
        const int idx = it * 256 + t;
        const int row = idx / 24, seg = idx - row * 24;
        *(uint4*)(XpB + (size_t)row * NL + seg * 8) =
            *(const uint4*)&Xob[row * 200 + seg * 8];
    }
}

// ---------------------------------------------------------------------------
// K1b: Xp[b][co][p=n*12+l] -> Xt[b][co*12+l][n]. (Unchanged from round 7.)
// ---------------------------------------------------------------------------
__global__ __launch_bounds__(256) void xt_transpose_kernel(
    const ushort_t* __restrict__ Xp, ushort_t* __restrict__ Xt)
{
    __shared__ ushort_t L[12 * 1032];   // [l][n pad 1032] 24768 B
    const int co = blockIdx.x, b = blockIdx.y, t = threadIdx.x;

    const ushort_t* src = Xp + ((size_t)b * COUT + co) * NL;
#pragma unroll
    for (int it = 0; it < 6; it++) {
        const int j = it * 256 + t;                  // uint4 index (0..1535)
        const uint4 v = *(const uint4*)(src + (size_t)j * 8);
        const uint_t wd0 = v.x, wd1 = v.y, wd2 = v.z, wd3 = v.w;
        int n = (j * 8) / 12, l = (j * 8) % 12;
        ushort_t e[8];
        e[0] = (ushort_t)(wd0 & 0xffff); e[1] = (ushort_t)(wd0 >> 16);
        e[2] = (ushort_t)(wd1 & 0xffff); e[3] = (ushort_t)(wd1 >> 16);
        e[4] = (ushort_t)(wd2 & 0xffff); e[5] = (ushort_t)(wd2 >> 16);
        e[6] = (ushort_t)(wd3 & 0xffff); e[7] = (ushort_t)(wd3 >> 16);
#pragma unroll
        for (int k = 0; k < 8; k++) {
            L[l * 1032 + n] = e[k];
            if (++l == 12) { l = 0; ++n; }
        }
    }
    __syncthreads();

    ushort_t* dst = Xt + ((size_t)b * CL + co * 12) * N_SZ;
#pragma unroll
    for (int it = 0; it < 6; it++) {
        const int j = it * 256 + t;                  // 12 l x 128 segs
        const int l = j >> 7, seg = j & 127;
        *(uint4*)&dst[(size_t)l * N_SZ + seg * 8] =
            *(const uint4*)&L[l * 1032 + seg * 8];
    }
}

// ---------------------------------------------------------------------------
// K2: z = leaky(f_i + f_j) + adj; row softmax; store S bf16 (row-major).
// (Unchanged.)
// ---------------------------------------------------------------------------
__global__ __launch_bounds__(256) void softmax_kernel(
    const float* __restrict__ adj, const float* __restrict__ f,
    ushort_t* __restrict__ Sb)
{
    __shared__ float smx[4], sms[4];
    const int i = blockIdx.x, b = blockIdx.y, t = threadIdx.x;
    const int lane = t & 63, wv = t >> 6;

    const float* frow = f + b * N_SZ;
    const float fi = frow[i];
    const float4 fj = *(const float4*)(frow + 4 * t);
    const float4 av = *(const float4*)(adj + ((size_t)b * N_SZ + i) * N_SZ + 4 * t);

    float z[4];
    z[0] = fi + fj.x; z[1] = fi + fj.y; z[2] = fi + fj.z; z[3] = fi + fj.w;
#pragma unroll
    for (int k = 0; k < 4; k++) z[k] = (z[k] >= 0.f) ? z[k] : ALPHA * z[k];
    z[0] += av.x; z[1] += av.y; z[2] += av.z; z[3] += av.w;

    float mx = fmaxf(fmaxf(z[0], z[1]), fmaxf(z[2], z[3]));
#pragma unroll
    for (int o = 32; o; o >>= 1) mx = fmaxf(mx, __shfl_xor(mx, o, 64));
    if (lane == 0) smx[wv] = mx;
    __syncthreads();
    mx = fmaxf(fmaxf(smx[0], smx[1]), fmaxf(smx[2], smx[3]));

    float e[4], s = 0.f;
#pragma unroll
    for (int k = 0; k < 4; k++) { e[k] = __expf(z[k] - mx); s += e[k]; }
#pragma unroll
    for (int o = 32; o; o >>= 1) s += __shfl_xor(s, o, 64);
    if (lane == 0) sms[wv] = s;
    __syncthreads();
    s = sms[0] + sms[1] + sms[2] + sms[3];
    const float inv = 1.0f / s;

    const uint_t p0 = (uint_t)f2bf(e[0] * inv) | ((uint_t)f2bf(e[1] * inv) << 16);
    const uint_t p1 = (uint_t)f2bf(e[2] * inv) | ((uint_t)f2bf(e[3] * inv) << 16);
    uint2 pk; pk.x = p0; pk.y = p1;
    *(uint2*)&Sb[((size_t)b * N_SZ + i) * N_SZ + 4 * t] = pk;
}

// ---------------------------------------------------------------------------
// K3: attention output = S^T, bf16 -> fp32, LDS 64x64 tile transpose.
// (Unchanged.)
// ---------------------------------------------------------------------------
__global__ __launch_bounds__(256) void att_transpose_kernel(
    const ushort_t* __restrict__ Sb, float* __restrict__ att)
{
    __shared__ float T[64][65];
    const int b = blockIdx.z;
    const int i0 = blockIdx.x * 64, j0 = blockIdx.y * 64;
    const int t = threadIdx.x;

#pragma unroll
    for (int ph = 0; ph < 2; ph++) {
        const int idx = ph * 256 + t;
        const int r = idx >> 3, c8 = (idx & 7) * 8;
        const uint4 v = *(const uint4*)(Sb + ((size_t)b * N_SZ + i0 + r) * N_SZ + j0 + c8);
        T[r][c8 + 0] = bf2f((ushort_t)(v.x & 0xffff));
        T[r][c8 + 1] = bf2f((ushort_t)(v.x >> 16));
        T[r][c8 + 2] = bf2f((ushort_t)(v.y & 0xffff));
        T[r][c8 + 3] = bf2f((ushort_t)(v.y >> 16));
        T[r][c8 + 4] = bf2f((ushort_t)(v.z & 0xffff));
        T[r][c8 + 5] = bf2f((ushort_t)(v.z >> 16));
        T[r][c8 + 6] = bf2f((ushort_t)(v.w & 0xffff));
        T[r][c8 + 7] = bf2f((ushort_t)(v.w >> 16));
    }
    __syncthreads();
#pragma unroll
    for (int ph = 0; ph < 4; ph++) {
        const int idx = ph * 256 + t;
        const int jr = idx >> 4, i4 = (idx & 15) * 4;
        float4 o;
        o.x = T[i4 + 0][jr]; o.y = T[i4 + 1][jr];
        o.z = T[i4 + 2][jr]; o.w = T[i4 + 3][jr];
        *(float4*)(att + ((size_t)b * N_SZ + j0 + jr) * N_SZ + i0 + i4) = o;
    }
}

// ---------------------------------------------------------------------------
// K4: per-batch GEMM  C[q,m] = sum_n S[q,n] * Xt[m,n], m=(co*12+l).
// R7 counters: dur 78.5us, FETCH 153MB (2.7x the 56MB ideal), MfmaUtil 12.6%
// -> HBM-fetch-bound; panels re-fetched because sharing blocks sat on
// different XCD L2s. Round-8 changes (this kernel only):
//  (a) batch-XCD swizzle: 1D grid 384, b = id%16 -> XCD(id%8) = b%8, so ALL
//      blocks of a batch share one XCD's L2 (per-XCD set: 2 batches x 3.5MB).
//  (b) BM=256 (m) x BQ=128 (q) tile, BK=32, double-buffered; 512 thr, 8
//      waves in 4m x 2q. Per-wave fragment/MFMA/epilogue code IDENTICAL to
//      the verified 128x128 kernel (Bs row-stride 128->256, wm now 2 bits).
//      Streamed bytes 24->18MB/batch, intensity 64->85 FLOP/B.
// LDS 2*(8+16)KB = 48KB; 3 blocks/CU. grid 384 = 16 b x (3 mx x 8 qy).
// ---------------------------------------------------------------------------
__global__ __launch_bounds__(512) void gemm2_kernel(
    const ushort_t* __restrict__ Sb, const ushort_t* __restrict__ Xt,
    float* __restrict__ out)
{
    __shared__ ushort_t As[2][128 * 32];      //  8 KB per buf: [kcs][qrow][8]
    __shared__ ushort_t Bs2[2][256 * 32];     // 16 KB per buf: [kcs][mrow][8]

    const int id = blockIdx.x;
    const int b  = id & 15;                   // XCD(id%8) == b%8: batch-local L2
    const int tile = id >> 4;                 // 0..23
    const int mx = tile % 3, qy = tile / 3;
    const int m0 = mx * 256, q0 = qy * 128;

    const int t = threadIdx.x;                // 0..511
    const int lane = t & 63, wv = t >> 6;
    const int wq = wv & 1, wm = wv >> 1;      // 2q x 4m wave grid
    const int kc = lane >> 4, rr = lane & 15;

    const ushort_t* Sbase = Sb + (size_t)b * N_SZ * N_SZ;
    const ushort_t* Xbase = Xt + (size_t)b * CL * N_SZ;

#define G2STAGE(bb, k0)                                                      \
    do {                                                                     \
        {   /* A: 128 q-rows x 32 k = 512 x 16B, one per thread */           \
            const int r = t & 127, kcs = t >> 7;                             \
            ASYNC16(&As[bb][t * 8],                                          \
                    Sbase + (size_t)(q0 + r) * N_SZ + (k0) + kcs * 8);       \
        }                                                                    \
        _Pragma("unroll")                                                    \
        for (int c = 0; c < 2; c++) { /* B: 256 m-rows x 32 k = 1024 x 16B */\
            const int u = c * 512 + t;                                       \
            const int r = u & 255, kcs = u >> 8;                             \
            ASYNC16(&Bs2[bb][u * 8],                                         \
                    Xbase + (size_t)(m0 + r) * N_SZ + (k0) + kcs * 8);       \
        }                                                                    \
    } while (0)

    floatx4 acc[4][4];
#pragma unroll
    for (int i = 0; i < 4; i++)
#pragma unroll
        for (int j = 0; j < 4; j++) acc[i][j] = (floatx4)0.f;

    G2STAGE(0, 0);
    __syncthreads();

    int cur = 0;
#pragma unroll 1
    for (int kt = 0; kt < 31; kt++) {
        G2STAGE(cur ^ 1, (kt + 1) * 32);

        bf16x8 af[4], bfr[4];
#pragma unroll
        for (int i = 0; i < 4; i++) {
            af[i]  = *(const bf16x8*)&As[cur][(kc * 128 + wq * 64 + i * 16 + rr) * 8];
            bfr[i] = *(const bf16x8*)&Bs2[cur][(kc * 256 + wm * 64 + i * 16 + rr) * 8];
        }
#pragma unroll
        for (int i = 0; i < 4; i++)
#pragma unroll
            for (int j = 0; j < 4; j++)
                acc[i][j] = __builtin_amdgcn_mfma_f32_16x16x32_bf16(
                    af[i], bfr[j], acc[i][j], 0, 0, 0);

        __syncthreads();
        cur ^= 1;
    }
    {   // last tile (kt = 31)
        bf16x8 af[4], bfr[4];
#pragma unroll
        for (int i = 0; i < 4; i++) {
            af[i]  = *(const bf16x8*)&As[cur][(kc * 128 + wq * 64 + i * 16 + rr) * 8];
            bfr[i] = *(const bf16x8*)&Bs2[cur][(kc * 256 + wm * 64 + i * 16 + rr) * 8];
        }
#pragma unroll
        for (int i = 0; i < 4; i++)
#pragma unroll
            for (int j = 0; j < 4; j++)
                acc[i][j] = __builtin_amdgcn_mfma_f32_16x16x32_bf16(
                    af[i], bfr[j], acc[i][j], 0, 0, 0);
    }
#undef G2STAGE

    // epilogue: C row = q (= kc*4 + reg within frag), col = m (= rr in frag)
#pragma unroll
    for (int j = 0; j < 4; j++) {
        const int m = m0 + wm * 64 + j * 16 + rr;
        const int co = m / 12, l = m - co * 12;
        float* ob = out + (size_t)(b * COUT + co) * (N_SZ * L_SZ) + l;
#pragma unroll
        for (int i = 0; i < 4; i++) {
            const int q = q0 + wq * 64 + i * 16 + kc * 4;
#pragma unroll
            for (int r2 = 0; r2 < 4; r2++)
                ob[(size_t)(q + r2) * 12] = acc[i][j][r2];
        }
    }
}

// ---------------------------------------------------------------------------
extern "C" void kernel_launch(void* const* d_in, const int* in_sizes, int n_in,
                              void* d_out, int out_size, void* d_ws, size_t ws_size,
                              hipStream_t stream)
{
    const float* inp = (const float*)d_in[0];
    const float* adj = (const float*)d_in[1];
    const float* w0  = (const float*)d_in[2];
    const float* b0  = (const float*)d_in[3];
    const float* w1  = (const float*)d_in[4];

    float* hprime = (float*)d_out;                       // 16*64*1024*12 fp32
    float* att    = hprime + (size_t)B_SZ * COUT * N_SZ * L_SZ;  // 64 MB region

    char* ws = (char*)d_ws;
    ushort_t* Xt = (ushort_t*)ws;                              // 25,165,824 B
    ushort_t* Sb = (ushort_t*)(ws + (size_t)25165824);         // 33,554,432 B
    float*    fw = (float*)(ws + (size_t)25165824 + 33554432); //     65,536 B

    // Scratch overlaid on the att region of d_out (consumed before
    // att_transpose overwrites it): Xp at offset 0 (25.2 MB), wt at +32 MB.
    ushort_t* Xp = (ushort_t*)att;
    _Float16* wt = (_Float16*)((char*)att + 33554432);         //     24,576 B

    prep_w_kernel<<<dim3(1), 256, 0, stream>>>(w0, wt);
    conv_mfma_kernel<<<dim3(64, B_SZ), 256, 0, stream>>>(inp, wt, b0, w1, Xp, fw);
    xt_transpose_kernel<<<dim3(COUT, B_SZ), 256, 0, stream>>>(Xp, Xt);
    softmax_kernel<<<dim3(N_SZ, B_SZ), 256, 0, stream>>>(adj, fw, Sb);
    att_transpose_kernel<<<dim3(N_SZ / 64, N_SZ / 64, B_SZ), 256, 0, stream>>>(Sb, att);
    gemm2_kernel<<<dim3(384), 512, 0, stream>>>(Sb, Xt, hprime);
}